// Round 7
// baseline (465.848 us; speedup 1.0000x reference)
//
#include <hip/hip_runtime.h>
#include <hip/hip_bf16.h>
#include <hip/hip_fp16.h>
#include <math.h>

// SportsGNN: ftMLP -> GATv2 x2 -> sumpool -> MLP -> softmax
// N=250000, E=5000000, H=2, O=8 (HO=16)
// Round-16: r11 structure with WAVE-UNIFORM HEAD assignment.
//  Diagnosis across r11-r15: dur ~= 2x VALU-busy, occupancy 22-39%,
//  per-wave issue-ready only ~25% -> latency-bound with too few waves.
//  All fast variants sat at VGPR 68-72, just over the 64 cliff
//  (waves/CU halves at >64). The 24 VGPRs of w0/w1/at are per-head
//  constants kept vector only because h was lane-varying.
//  Fix: block = 128 nodes x 2 heads; waves 0-1 head0, waves 2-3 head1;
//  hu = readfirstlane(h) -> we/att/bias/wl2/bl2/wr2/br2 become SGPR
//  scalar loads. __launch_bounds__(256,8) forces VGPR<=64 -> 32 waves/CU.
//  Head exchange for fused layer-2 via 8KB LDS (one barrier) instead of
//  shfl_xor. Everything else identical to r11 (plain loads, 4-deep batch).

#define HO 16
#define BSHIFT 8
#define BNODES 256
#define PT 512          // k_part threads
#define PCHUNK 6144     // edges per partition block
#define CAP2 6016       // per-bucket record capacity (mean ~5117, +12.6 sigma)

typedef __attribute__((ext_vector_type(2))) float v2f;

__device__ __forceinline__ float lrelu(float x, float s) { return x > 0.f ? x : s * x; }

// pack 8 floats -> 8 fp8 bytes (e4m3 HW rounding)
__device__ __forceinline__ uint2 pack_fp8x8(const float* v) {
    int a = __builtin_amdgcn_cvt_pk_fp8_f32(v[0], v[1], 0, false);
    a     = __builtin_amdgcn_cvt_pk_fp8_f32(v[2], v[3], a, true);
    int b = __builtin_amdgcn_cvt_pk_fp8_f32(v[4], v[5], 0, false);
    b     = __builtin_amdgcn_cvt_pk_fp8_f32(v[6], v[7], b, true);
    return make_uint2((unsigned int)a, (unsigned int)b);
}

// unpack 8 fp8 bytes -> 8 floats
__device__ __forceinline__ void unpack_fp8x8(uint2 u, float* v) {
    v2f f0 = __builtin_amdgcn_cvt_pk_f32_fp8((int)u.x, false);
    v2f f1 = __builtin_amdgcn_cvt_pk_f32_fp8((int)u.x, true);
    v2f f2 = __builtin_amdgcn_cvt_pk_f32_fp8((int)u.y, false);
    v2f f3 = __builtin_amdgcn_cvt_pk_f32_fp8((int)u.y, true);
    v[0]=f0.x; v[1]=f0.y; v[2]=f1.x; v[3]=f1.y;
    v[4]=f2.x; v[5]=f2.y; v[6]=f3.x; v[7]=f3.y;
}

// ---------------- node kernel, layer 1: x[N,3] -> ftMLP -> xlA(fp8), xr(fp32) ----------------
__global__ void __launch_bounds__(256) node_l1(
    const float* __restrict__ x,
    const float* __restrict__ ft1_w, const float* __restrict__ ft1_b,
    const float* __restrict__ ft2_w, const float* __restrict__ ft2_b,
    const float* __restrict__ wl, const float* __restrict__ bl,
    const float* __restrict__ wr, const float* __restrict__ br,
    uint2* __restrict__ xlA, float* __restrict__ xr, int N)
{
    int n = blockIdx.x * 256 + threadIdx.x;
    if (n >= N) return;
    float x0 = x[3*n], x1 = x[3*n+1], x2 = x[3*n+2];
    float h1[8];
#pragma unroll
    for (int j = 0; j < 8; j++) {
        float a = ft1_w[3*j]*x0 + ft1_w[3*j+1]*x1 + ft1_w[3*j+2]*x2 + ft1_b[j];
        h1[j] = lrelu(a, 0.1f);
    }
    float h2[8];
#pragma unroll
    for (int j = 0; j < 8; j++) {
        float a = ft2_b[j];
#pragma unroll
        for (int k = 0; k < 8; k++) a += ft2_w[8*j+k]*h1[k];
        h2[j] = lrelu(a, 0.1f);
    }
    float ol[HO], orr[HO];
#pragma unroll
    for (int j = 0; j < HO; j++) {
        float a = bl[j], b = br[j];
#pragma unroll
        for (int k = 0; k < 8; k++) { a += wl[8*j+k]*h2[k]; b += wr[8*j+k]*h2[k]; }
        ol[j] = a; orr[j] = b;
    }
    uint2 p0 = pack_fp8x8(ol);
    uint2 p1 = pack_fp8x8(ol + 8);
    ((uint4*)xlA)[n] = make_uint4(p0.x, p0.y, p1.x, p1.y);
    float4* xr4 = (float4*)(xr + (size_t)n*HO);
#pragma unroll
    for (int q = 0; q < 4; q++)
        xr4[q] = make_float4(orr[4*q], orr[4*q+1], orr[4*q+2], orr[4*q+3]);
}

// bucket cursors: bcur[b] = b*CAP2 (start of each padded region)
__global__ void __launch_bounds__(256) k_binit(int* __restrict__ bcur)
{
    int b = blockIdx.x * 256 + threadIdx.x;
    if (b < 1024) bcur[b] = b * CAP2;
}

// ---------------- phase 1: LDS multisplit into padded bucket regions ----------------
// out rec: .x = (src<<8)|(dst&255), .y = half2(eattr)
__global__ void __launch_bounds__(PT) k_part(
    const int* __restrict__ src, const int* __restrict__ dst,
    const float* __restrict__ eattr, int* __restrict__ bcur,
    uint2* __restrict__ grecs, int E)
{
    __shared__ int hist[1024], lofs[1024], gofs[1024], lcur[1024];
    __shared__ int scan_s[PT];
    __shared__ uint2 srecs[PCHUNK];
    __shared__ unsigned short bid[PCHUNK];
    int t = threadIdx.x;
    int base = blockIdx.x * PCHUNK;
    int cnt = E - base; if (cnt > PCHUNK) cnt = PCHUNK;

    for (int b = t; b < 1024; b += PT) hist[b] = 0;
    __syncthreads();
    for (int i = t; i < cnt; i += PT)
        atomicAdd(&hist[dst[base + i] >> BSHIFT], 1);
    __syncthreads();
    int h0 = hist[2*t], h1 = hist[2*t+1];
    int pair = h0 + h1;
    scan_s[t] = pair;
    __syncthreads();
    for (int off = 1; off < PT; off <<= 1) {
        int add = (t >= off) ? scan_s[t - off] : 0;
        __syncthreads();
        scan_s[t] += add;
        __syncthreads();
    }
    int pbase = scan_s[t] - pair;
    lofs[2*t]   = pbase;
    lofs[2*t+1] = pbase + h0;
    __syncthreads();
    for (int b = t; b < 1024; b += PT) {
        int c = hist[b];
        int g = (c > 0) ? atomicAdd(&bcur[b], c) : 0;
        gofs[b] = g - lofs[b];
        lcur[b] = 0;
    }
    __syncthreads();
    for (int i = t; i < cnt; i += PT) {
        int e = base + i;
        int d = dst[e];
        int b = d >> BSHIFT;
        float2 ea = ((const float2*)eattr)[e];
        __half2 hv = __floats2half2_rn(ea.x, ea.y);
        unsigned int eb = *reinterpret_cast<unsigned int*>(&hv);
        int q = atomicAdd(&lcur[b], 1);
        int idx = lofs[b] + q;
        srecs[idx] = make_uint2(((unsigned int)src[e] << 8) | (unsigned int)(d & (BNODES-1)), eb);
        bid[idx] = (unsigned short)b;
    }
    __syncthreads();
    for (int i = t; i < cnt; i += PT) {
        int b = bid[i];
        int pos = gofs[b] + i;
        if (pos < (b + 1) * CAP2) grecs[pos] = srecs[i];
    }
}

// ---------------- phase 2: per-bucket in-LDS node sort + rowS/rowE emission ----------------
__global__ void __launch_bounds__(256) k_fine(
    const int* __restrict__ bcur, uint2* recs,
    int* __restrict__ rowS, int* __restrict__ rowE, int N)
{
    __shared__ uint2 rout[CAP2];
    __shared__ int lhist[256], lsc[256], lcur2[256];
    int b = blockIdx.x;
    int bstart = b * CAP2;
    int cnt = bcur[b] - bstart;
    if (cnt > CAP2) cnt = CAP2;
    if (cnt < 0) cnt = 0;
    int t = threadIdx.x;
    lhist[t] = 0;
    __syncthreads();
    for (int i = t; i < cnt; i += 256)
        atomicAdd(&lhist[recs[bstart + i].x & (BNODES-1)], 1);
    __syncthreads();
    int v = lhist[t];
    lsc[t] = v;
    __syncthreads();
    for (int off = 1; off < 256; off <<= 1) {
        int add = (t >= off) ? lsc[t - off] : 0;
        __syncthreads();
        lsc[t] += add;
        __syncthreads();
    }
    int ex = lsc[t] - v;      // exclusive in-bucket prefix
    lcur2[t] = ex;
    int n = (b << BSHIFT) + t;
    if (n < N) { rowS[n] = bstart + ex; rowE[n] = bstart + ex + v; }
    __syncthreads();
    for (int i = t; i < cnt; i += 256) {
        uint2 r = recs[bstart + i];
        int p = atomicAdd(&lcur2[r.x & (BNODES-1)], 1);
        rout[p] = make_uint2(r.x >> 8, r.y);
    }
    __syncthreads();
    for (int i = t; i < cnt; i += 256)
        recs[bstart + i] = rout[i];
}

// ---------------- per-(node,head) online-softmax aggregation ----------------
struct AggState { float m, s, acc[8]; };

__device__ __forceinline__ void agg_edge(
    AggState& st, const float* va, const float* xd,
    const float* w0, const float* w1, const float* at,
    float ea0, float ea1)
{
    float lg = 0.f;
#pragma unroll
    for (int o = 0; o < 8; o++) {
        float mv = va[o] + xd[o] + (w0[o]*ea0 + w1[o]*ea1);
        mv = mv > 0.f ? mv : 0.2f*mv;      // leaky_relu 0.2
        lg += mv * at[o];
    }
    float nm = fmaxf(st.m, lg);
    float sc = __expf(st.m - nm);
    float wv = __expf(lg - nm);
    st.s = st.s*sc + wv;
#pragma unroll
    for (int o = 0; o < 8; o++) st.acc[o] = st.acc[o]*sc + wv*va[o];
    st.m = nm;
}

__device__ __forceinline__ void agg_one(
    AggState& st, uint2 r, uint2 g, const float* xd,
    const float* w0, const float* w1, const float* at)
{
    float v[8];
    unpack_fp8x8(g, v);
    __half2 h2 = *reinterpret_cast<__half2*>(&r.y);
    agg_edge(st, v, xd, w0, w1, at, __low2float(h2), __high2float(h2));
}

// online-softmax over one (node,head) row; hu is wave-uniform (SGPR)
__device__ __forceinline__ void agg_row(
    int rs, int re, int hu,
    const uint2* __restrict__ recs, const uint2* __restrict__ xl8,
    const float* xd, const float* w0, const float* w1, const float* at,
    AggState& st)
{
    st.m = -INFINITY; st.s = 0.f;
#pragma unroll
    for (int o = 0; o < 8; o++) st.acc[o] = 0.f;
    int i = rs;
    for (; i + 4 <= re; i += 4) {
        uint2 r0 = recs[i], r1 = recs[i+1], r2 = recs[i+2], r3 = recs[i+3];
        uint2 g0 = xl8[(size_t)r0.x*2 + hu];
        uint2 g1 = xl8[(size_t)r1.x*2 + hu];
        uint2 g2 = xl8[(size_t)r2.x*2 + hu];
        uint2 g3 = xl8[(size_t)r3.x*2 + hu];
        agg_one(st, r0, g0, xd, w0, w1, at);
        agg_one(st, r1, g1, xd, w0, w1, at);
        agg_one(st, r2, g2, xd, w0, w1, at);
        agg_one(st, r3, g3, xd, w0, w1, at);
    }
    for (; i < re; i++) {
        uint2 r0 = recs[i];
        uint2 g0 = xl8[(size_t)r0.x*2 + hu];
        agg_one(st, r0, g0, xd, w0, w1, at);
    }
}

// layer 1 fused: aggregate + lrelu(0.1) + layer-2 transform -> xlB(fp8), xr(in place)
// block = 128 nodes x 2 heads; waves 0-1: head 0, waves 2-3: head 1.
__global__ void __launch_bounds__(256, 8) node_agg_l1(
    const int* __restrict__ rowS, const int* __restrict__ rowE,
    const uint2* __restrict__ recs,
    const uint2* __restrict__ xlA, float* xr,
    const float* __restrict__ we, const float* __restrict__ att,
    const float* __restrict__ bias,
    const float* __restrict__ wl2, const float* __restrict__ bl2,
    const float* __restrict__ wr2, const float* __restrict__ br2,
    uint2* __restrict__ xlB, int N)
{
    __shared__ float sh[256][8];
    int t = threadIdx.x;
    int hu = __builtin_amdgcn_readfirstlane(t >> 7);   // wave-uniform head
    int n = blockIdx.x * 128 + (t & 127);
    bool alive = (n < N);
    int kb = hu * 8;
    float w0[8], w1[8], at[8];                          // SGPR (uniform idx)
#pragma unroll
    for (int o = 0; o < 8; o++) {
        w0[o] = we[2*(kb+o)];
        w1[o] = we[2*(kb+o)+1];
        at[o] = att[kb+o];
    }
    float xd[8];
    {
        size_t nn = alive ? (size_t)n : 0;
        const float4* xrp = (const float4*)(xr + nn*HO + kb);
        float4 d0 = xrp[0], d1 = xrp[1];
        xd[0]=d0.x; xd[1]=d0.y; xd[2]=d0.z; xd[3]=d0.w;
        xd[4]=d1.x; xd[5]=d1.y; xd[6]=d1.z; xd[7]=d1.w;
    }
    int rs = alive ? rowS[n] : 0;
    int re = alive ? rowE[n] : 0;
    AggState st;
    agg_row(rs, re, hu, recs, xlA, xd, w0, w1, at, st);

    float inv = 1.f/(st.s + 1e-16f);
    float hh[8];
#pragma unroll
    for (int o = 0; o < 8; o++) hh[o] = lrelu(st.acc[o]*inv + bias[kb+o], 0.1f);
    // exchange with the other head's thread (t ^ 128) via LDS
#pragma unroll
    for (int o = 0; o < 8; o++) sh[t][o] = hh[o];
    __syncthreads();
    if (!alive) return;
    int partner = t ^ 128;
    float h0v[8], h1v[8];
#pragma unroll
    for (int o = 0; o < 8; o++) {
        float oth = sh[partner][o];
        h0v[o] = hu ? oth : hh[o];
        h1v[o] = hu ? hh[o] : oth;
    }
    // layer-2 transform: this thread computes its head's 8 outputs of xl2, xr2
    float ol[8], orr[8];
#pragma unroll
    for (int jo = 0; jo < 8; jo++) {
        int j = kb + jo;
        float a = bl2[j], b = br2[j];
#pragma unroll
        for (int k = 0; k < 8; k++) { a += wl2[HO*j+k]*h0v[k];   b += wr2[HO*j+k]*h0v[k]; }
#pragma unroll
        for (int k = 0; k < 8; k++) { a += wl2[HO*j+8+k]*h1v[k]; b += wr2[HO*j+8+k]*h1v[k]; }
        ol[jo] = a; orr[jo] = b;
    }
    xlB[(size_t)n*2 + hu] = pack_fp8x8(ol);
    float4* xr4 = (float4*)(xr + (size_t)n*HO + kb);
    xr4[0] = make_float4(orr[0], orr[1], orr[2], orr[3]);
    xr4[1] = make_float4(orr[4], orr[5], orr[6], orr[7]);
}

// layer 2: aggregate (+bias), block-reduce, write partials column-major
__global__ void __launch_bounds__(256, 8) node_agg_l2(
    const int* __restrict__ rowS, const int* __restrict__ rowE,
    const uint2* __restrict__ recs,
    const uint2* __restrict__ xlB, const float* __restrict__ xr,
    const float* __restrict__ we, const float* __restrict__ att,
    const float* __restrict__ bias, float* __restrict__ partials, int pstride, int N)
{
    int t = threadIdx.x;
    int hu = __builtin_amdgcn_readfirstlane(t >> 7);   // wave-uniform head
    int n = blockIdx.x * 128 + (t & 127);
    bool alive = (n < N);
    int kb = hu * 8;
    float w0[8], w1[8], at[8];
#pragma unroll
    for (int o = 0; o < 8; o++) {
        w0[o] = we[2*(kb+o)];
        w1[o] = we[2*(kb+o)+1];
        at[o] = att[kb+o];
    }
    float xd[8];
    {
        size_t nn = alive ? (size_t)n : 0;
        const float4* xrp = (const float4*)(xr + nn*HO + kb);
        float4 d0 = xrp[0], d1 = xrp[1];
        xd[0]=d0.x; xd[1]=d0.y; xd[2]=d0.z; xd[3]=d0.w;
        xd[4]=d1.x; xd[5]=d1.y; xd[6]=d1.z; xd[7]=d1.w;
    }
    int rs = alive ? rowS[n] : 0;
    int re = alive ? rowE[n] : 0;
    AggState st;
    agg_row(rs, re, hu, recs, xlB, xd, w0, w1, at, st);

    float out[8];
    if (alive) {
        float inv = 1.f/(st.s + 1e-16f);
#pragma unroll
        for (int o = 0; o < 8; o++) out[o] = st.acc[o]*inv + bias[kb+o];
    } else {
#pragma unroll
        for (int o = 0; o < 8; o++) out[o] = 0.f;
    }
    // wave reduce (all lanes in a wave share the same head)
#pragma unroll
    for (int off = 32; off >= 1; off >>= 1) {
#pragma unroll
        for (int o = 0; o < 8; o++) out[o] += __shfl_down(out[o], off, 64);
    }
    __shared__ float sm[4][8];
    int wave = t >> 6, lane = t & 63;
    if (lane == 0) {
#pragma unroll
        for (int o = 0; o < 8; o++) sm[wave][o] = out[o];
    }
    __syncthreads();
    if (t < 16) {
        int hp = t >> 3, oo = t & 7;            // waves 0,1 = head0; 2,3 = head1
        float tt = sm[2*hp][oo] + sm[2*hp+1][oo];
        partials[(size_t)(hp*8 + oo) * pstride + blockIdx.x] = tt;
    }
}

// parallel partials fold: one block per column, coalesced reads
__global__ void __launch_bounds__(256) k_reduce(
    const float* __restrict__ partials, int pstride, int nparts,
    float* __restrict__ pool)
{
    __shared__ float s[256];
    int c = blockIdx.x;           // column 0..15
    int t = threadIdx.x;
    const float* col = partials + (size_t)c * pstride;
    float acc = 0.f;
    for (int r = t; r < nparts; r += 256) acc += col[r];
    s[t] = acc;
    __syncthreads();
#pragma unroll
    for (int off = 128; off > 0; off >>= 1) {
        if (t < off) s[t] += s[t + off];
        __syncthreads();
    }
    if (t == 0) pool[c] = s[0];
}

// ---------------- final tail (pool[16] precomputed) ----------------
__global__ void __launch_bounds__(64) final_mlp(
    const float* __restrict__ pool, const float* __restrict__ meta,
    const float* __restrict__ sp1_w, const float* __restrict__ sp1_b,
    const float* __restrict__ sp2_w, const float* __restrict__ sp2_b,
    const float* __restrict__ me_w, const float* __restrict__ me_b,
    const float* __restrict__ fc1_w, const float* __restrict__ fc1_b,
    const float* __restrict__ fc2_w, const float* __restrict__ fc2_b,
    const float* __restrict__ fc3_w, const float* __restrict__ fc3_b,
    float* __restrict__ out)
{
    __shared__ float s1[64], zb[24], z1[24], z2[8];
    int t = threadIdx.x;
    {
        float acc = sp1_b[t];
        for (int k = 0; k < 16; k++) acc += pool[k]*sp1_w[t*16+k];
        s1[t] = lrelu(acc, 0.1f);
    }
    __syncthreads();
    if (t < 16) {
        float acc = sp2_b[t];
        for (int k = 0; k < 64; k++) acc += s1[k]*sp2_w[t*64+k];
        zb[t] = acc;
    } else if (t < 24) {
        int j = t - 16;
        float acc = me_b[j];
        for (int k = 0; k < 6; k++) acc += meta[k]*me_w[j*6+k];
        zb[t] = lrelu(acc, 0.1f);
    }
    __syncthreads();
    if (t < 24) {
        float acc = fc1_b[t];
        for (int k = 0; k < 24; k++) acc += zb[k]*fc1_w[t*24+k];
        z1[t] = lrelu(acc, 0.1f);
    }
    __syncthreads();
    if (t < 8) {
        float acc = fc2_b[t];
        for (int k = 0; k < 24; k++) acc += z1[k]*fc2_w[t*24+k];
        z2[t] = lrelu(acc, 0.1f);
    }
    __syncthreads();
    if (t == 0) {
        float z3[3]; float mxv = -1e30f;
        for (int j = 0; j < 3; j++) {
            float acc = fc3_b[j];
            for (int k = 0; k < 8; k++) acc += z2[k]*fc3_w[j*8+k];
            z3[j] = acc; mxv = fmaxf(mxv, acc);
        }
        float s = 0.f;
        for (int j = 0; j < 3; j++) { z3[j] = __expf(z3[j]-mxv); s += z3[j]; }
        for (int j = 0; j < 3; j++) out[j] = z3[j]/s;
    }
}

extern "C" void kernel_launch(void* const* d_in, const int* in_sizes, int n_in,
                              void* d_out, int out_size, void* d_ws, size_t ws_size,
                              hipStream_t stream)
{
    const float* x      = (const float*)d_in[0];
    const int*   eidx   = (const int*)  d_in[1];
    const float* eattr  = (const float*)d_in[2];
    const float* meta   = (const float*)d_in[3];
    const float* ft1_w  = (const float*)d_in[4];
    const float* ft1_b  = (const float*)d_in[5];
    const float* ft2_w  = (const float*)d_in[6];
    const float* ft2_b  = (const float*)d_in[7];
    const float* g1_wl  = (const float*)d_in[8];
    const float* g1_bl  = (const float*)d_in[9];
    const float* g1_wr  = (const float*)d_in[10];
    const float* g1_br  = (const float*)d_in[11];
    const float* g1_we  = (const float*)d_in[12];
    const float* g1_att = (const float*)d_in[13];
    const float* g1_bias= (const float*)d_in[14];
    const float* g2_wl  = (const float*)d_in[15];
    const float* g2_bl  = (const float*)d_in[16];
    const float* g2_wr  = (const float*)d_in[17];
    const float* g2_br  = (const float*)d_in[18];
    const float* g2_we  = (const float*)d_in[19];
    const float* g2_att = (const float*)d_in[20];
    const float* g2_bias= (const float*)d_in[21];
    const float* sp1_w  = (const float*)d_in[22];
    const float* sp1_b  = (const float*)d_in[23];
    const float* sp2_w  = (const float*)d_in[24];
    const float* sp2_b  = (const float*)d_in[25];
    const float* me_w   = (const float*)d_in[26];
    const float* me_b   = (const float*)d_in[27];
    const float* fc1_w  = (const float*)d_in[28];
    const float* fc1_b  = (const float*)d_in[29];
    const float* fc2_w  = (const float*)d_in[30];
    const float* fc2_b  = (const float*)d_in[31];
    const float* fc3_w  = (const float*)d_in[32];
    const float* fc3_b  = (const float*)d_in[33];
    float* out = (float*)d_out;

    const int N = in_sizes[0] / 3;
    const int E = in_sizes[2] / 2;
    const int* src = eidx;
    const int* dst = eidx + E;

    const int BN    = (N + 255) / 256;
    const int BN2   = (2*N + 255) / 256;           // agg kernels: 2 threads/node
    const int NBUCK = (N + BNODES - 1) >> BSHIFT;  // 977 (<= 1024)
    const int BP    = (E + PCHUNK - 1) / PCHUNK;   // partition blocks
    const int pstride = (BN2 + 63) & ~63;          // column-major partials stride

    // workspace layout (256B-aligned):
    char* w = (char*)d_ws;
    size_t off = 0;
    auto take = [&](size_t bytes) { size_t o = off; off += (bytes + 255) & ~(size_t)255; return o; };
    int*    rowS     = (int*)   (w + take((size_t)4*N));
    int*    rowE     = (int*)   (w + take((size_t)4*N));
    int*    bcur     = (int*)   (w + take(4096));
    float*  pool     = (float*) (w + take(64));
    float*  partials = (float*) (w + take((size_t)4*16*pstride));
    uint2*  recs     = (uint2*) (w + take((size_t)8*NBUCK*CAP2));  // padded regions
    uint2*  xlA      = (uint2*) (w + take((size_t)16*N));          // fp8 table, layer 1
    uint2*  xlB      = (uint2*) (w + take((size_t)16*N));          // fp8 table, layer 2
    float*  xr       = (float*) (w + take((size_t)64*N));          // fp32, in-place update
    // total ~= 2MB + 45MB + 4MB + 4MB + 16MB ~= 71MB

    // node features + layer-1 transforms
    node_l1<<<BN, 256, 0, stream>>>(x, ft1_w, ft1_b, ft2_w, ft2_b,
                                    g1_wl, g1_bl, g1_wr, g1_br, xlA, xr, N);
    // two-phase dst-sort into padded bucket regions (graph-only; shared by both layers)
    k_binit<<<4, 256, 0, stream>>>(bcur);
    k_part<<<BP, PT, 0, stream>>>(src, dst, eattr, bcur, recs, E);
    k_fine<<<NBUCK, 256, 0, stream>>>(bcur, recs, rowS, rowE, N);

    // ---- layer 1 (agg + act + layer-2 transform fused) ----
    node_agg_l1<<<BN2, 256, 0, stream>>>(rowS, rowE, recs, xlA, xr,
                                         g1_we, g1_att, g1_bias,
                                         g2_wl, g2_bl, g2_wr, g2_br, xlB, N);
    // ---- layer 2 ----
    node_agg_l2<<<BN2, 256, 0, stream>>>(rowS, rowE, recs, xlB, xr,
                                         g2_we, g2_att, g2_bias, partials, pstride, N);
    // ---- tail ----
    k_reduce<<<16, 256, 0, stream>>>(partials, pstride, BN2, pool);
    final_mlp<<<1, 64, 0, stream>>>(pool, meta, sp1_w, sp1_b, sp2_w, sp2_b,
                                    me_w, me_b, fc1_w, fc1_b, fc2_w, fc2_b,
                                    fc3_w, fc3_b, out);
}

// Round 8
// 448.449 us; speedup vs baseline: 1.0388x; 1.0388x over previous
//
#include <hip/hip_runtime.h>
#include <hip/hip_bf16.h>
#include <hip/hip_fp16.h>
#include <math.h>

// SportsGNN: ftMLP -> GATv2 x2 -> sumpool -> MLP -> softmax
// N=250000, E=5000000, H=2, O=8 (HO=16)
// Round-17: r16 (wave-uniform head -> SGPR attention constants; occupancy
// 26->64% CONFIRMED) minus the spill: __launch_bounds__(256,4) instead of
// (256,8). r16's forced 8-waves/EU budget made the compiler emit
// VGPR_Count=32 kernels that spilled the accumulator in the edge loop --
// node_agg_l2 showed 53.8MB WRITE_SIZE (architectural writes: ~125KB) and
// FETCH 276MB. Budget 128 lets it land at its natural ~50 VGPRs; HW
// occupancy follows ACTUAL vgpr count, so <=64 still yields 8 waves/SIMD.

#define HO 16
#define BSHIFT 8
#define BNODES 256
#define PT 512          // k_part threads
#define PCHUNK 6144     // edges per partition block
#define CAP2 6016       // per-bucket record capacity (mean ~5117, +12.6 sigma)

typedef __attribute__((ext_vector_type(2))) float v2f;

__device__ __forceinline__ float lrelu(float x, float s) { return x > 0.f ? x : s * x; }

// pack 8 floats -> 8 fp8 bytes (e4m3 HW rounding)
__device__ __forceinline__ uint2 pack_fp8x8(const float* v) {
    int a = __builtin_amdgcn_cvt_pk_fp8_f32(v[0], v[1], 0, false);
    a     = __builtin_amdgcn_cvt_pk_fp8_f32(v[2], v[3], a, true);
    int b = __builtin_amdgcn_cvt_pk_fp8_f32(v[4], v[5], 0, false);
    b     = __builtin_amdgcn_cvt_pk_fp8_f32(v[6], v[7], b, true);
    return make_uint2((unsigned int)a, (unsigned int)b);
}

// unpack 8 fp8 bytes -> 8 floats
__device__ __forceinline__ void unpack_fp8x8(uint2 u, float* v) {
    v2f f0 = __builtin_amdgcn_cvt_pk_f32_fp8((int)u.x, false);
    v2f f1 = __builtin_amdgcn_cvt_pk_f32_fp8((int)u.x, true);
    v2f f2 = __builtin_amdgcn_cvt_pk_f32_fp8((int)u.y, false);
    v2f f3 = __builtin_amdgcn_cvt_pk_f32_fp8((int)u.y, true);
    v[0]=f0.x; v[1]=f0.y; v[2]=f1.x; v[3]=f1.y;
    v[4]=f2.x; v[5]=f2.y; v[6]=f3.x; v[7]=f3.y;
}

// ---------------- node kernel, layer 1: x[N,3] -> ftMLP -> xlA(fp8), xr(fp32) ----------------
__global__ void __launch_bounds__(256) node_l1(
    const float* __restrict__ x,
    const float* __restrict__ ft1_w, const float* __restrict__ ft1_b,
    const float* __restrict__ ft2_w, const float* __restrict__ ft2_b,
    const float* __restrict__ wl, const float* __restrict__ bl,
    const float* __restrict__ wr, const float* __restrict__ br,
    uint2* __restrict__ xlA, float* __restrict__ xr, int N)
{
    int n = blockIdx.x * 256 + threadIdx.x;
    if (n >= N) return;
    float x0 = x[3*n], x1 = x[3*n+1], x2 = x[3*n+2];
    float h1[8];
#pragma unroll
    for (int j = 0; j < 8; j++) {
        float a = ft1_w[3*j]*x0 + ft1_w[3*j+1]*x1 + ft1_w[3*j+2]*x2 + ft1_b[j];
        h1[j] = lrelu(a, 0.1f);
    }
    float h2[8];
#pragma unroll
    for (int j = 0; j < 8; j++) {
        float a = ft2_b[j];
#pragma unroll
        for (int k = 0; k < 8; k++) a += ft2_w[8*j+k]*h1[k];
        h2[j] = lrelu(a, 0.1f);
    }
    float ol[HO], orr[HO];
#pragma unroll
    for (int j = 0; j < HO; j++) {
        float a = bl[j], b = br[j];
#pragma unroll
        for (int k = 0; k < 8; k++) { a += wl[8*j+k]*h2[k]; b += wr[8*j+k]*h2[k]; }
        ol[j] = a; orr[j] = b;
    }
    uint2 p0 = pack_fp8x8(ol);
    uint2 p1 = pack_fp8x8(ol + 8);
    ((uint4*)xlA)[n] = make_uint4(p0.x, p0.y, p1.x, p1.y);
    float4* xr4 = (float4*)(xr + (size_t)n*HO);
#pragma unroll
    for (int q = 0; q < 4; q++)
        xr4[q] = make_float4(orr[4*q], orr[4*q+1], orr[4*q+2], orr[4*q+3]);
}

// bucket cursors: bcur[b] = b*CAP2 (start of each padded region)
__global__ void __launch_bounds__(256) k_binit(int* __restrict__ bcur)
{
    int b = blockIdx.x * 256 + threadIdx.x;
    if (b < 1024) bcur[b] = b * CAP2;
}

// ---------------- phase 1: LDS multisplit into padded bucket regions ----------------
// out rec: .x = (src<<8)|(dst&255), .y = half2(eattr)
__global__ void __launch_bounds__(PT) k_part(
    const int* __restrict__ src, const int* __restrict__ dst,
    const float* __restrict__ eattr, int* __restrict__ bcur,
    uint2* __restrict__ grecs, int E)
{
    __shared__ int hist[1024], lofs[1024], gofs[1024], lcur[1024];
    __shared__ int scan_s[PT];
    __shared__ uint2 srecs[PCHUNK];
    __shared__ unsigned short bid[PCHUNK];
    int t = threadIdx.x;
    int base = blockIdx.x * PCHUNK;
    int cnt = E - base; if (cnt > PCHUNK) cnt = PCHUNK;

    for (int b = t; b < 1024; b += PT) hist[b] = 0;
    __syncthreads();
    for (int i = t; i < cnt; i += PT)
        atomicAdd(&hist[dst[base + i] >> BSHIFT], 1);
    __syncthreads();
    int h0 = hist[2*t], h1 = hist[2*t+1];
    int pair = h0 + h1;
    scan_s[t] = pair;
    __syncthreads();
    for (int off = 1; off < PT; off <<= 1) {
        int add = (t >= off) ? scan_s[t - off] : 0;
        __syncthreads();
        scan_s[t] += add;
        __syncthreads();
    }
    int pbase = scan_s[t] - pair;
    lofs[2*t]   = pbase;
    lofs[2*t+1] = pbase + h0;
    __syncthreads();
    for (int b = t; b < 1024; b += PT) {
        int c = hist[b];
        int g = (c > 0) ? atomicAdd(&bcur[b], c) : 0;
        gofs[b] = g - lofs[b];
        lcur[b] = 0;
    }
    __syncthreads();
    for (int i = t; i < cnt; i += PT) {
        int e = base + i;
        int d = dst[e];
        int b = d >> BSHIFT;
        float2 ea = ((const float2*)eattr)[e];
        __half2 hv = __floats2half2_rn(ea.x, ea.y);
        unsigned int eb = *reinterpret_cast<unsigned int*>(&hv);
        int q = atomicAdd(&lcur[b], 1);
        int idx = lofs[b] + q;
        srecs[idx] = make_uint2(((unsigned int)src[e] << 8) | (unsigned int)(d & (BNODES-1)), eb);
        bid[idx] = (unsigned short)b;
    }
    __syncthreads();
    for (int i = t; i < cnt; i += PT) {
        int b = bid[i];
        int pos = gofs[b] + i;
        if (pos < (b + 1) * CAP2) grecs[pos] = srecs[i];
    }
}

// ---------------- phase 2: per-bucket in-LDS node sort + rowS/rowE emission ----------------
__global__ void __launch_bounds__(256) k_fine(
    const int* __restrict__ bcur, uint2* recs,
    int* __restrict__ rowS, int* __restrict__ rowE, int N)
{
    __shared__ uint2 rout[CAP2];
    __shared__ int lhist[256], lsc[256], lcur2[256];
    int b = blockIdx.x;
    int bstart = b * CAP2;
    int cnt = bcur[b] - bstart;
    if (cnt > CAP2) cnt = CAP2;
    if (cnt < 0) cnt = 0;
    int t = threadIdx.x;
    lhist[t] = 0;
    __syncthreads();
    for (int i = t; i < cnt; i += 256)
        atomicAdd(&lhist[recs[bstart + i].x & (BNODES-1)], 1);
    __syncthreads();
    int v = lhist[t];
    lsc[t] = v;
    __syncthreads();
    for (int off = 1; off < 256; off <<= 1) {
        int add = (t >= off) ? lsc[t - off] : 0;
        __syncthreads();
        lsc[t] += add;
        __syncthreads();
    }
    int ex = lsc[t] - v;      // exclusive in-bucket prefix
    lcur2[t] = ex;
    int n = (b << BSHIFT) + t;
    if (n < N) { rowS[n] = bstart + ex; rowE[n] = bstart + ex + v; }
    __syncthreads();
    for (int i = t; i < cnt; i += 256) {
        uint2 r = recs[bstart + i];
        int p = atomicAdd(&lcur2[r.x & (BNODES-1)], 1);
        rout[p] = make_uint2(r.x >> 8, r.y);
    }
    __syncthreads();
    for (int i = t; i < cnt; i += 256)
        recs[bstart + i] = rout[i];
}

// ---------------- per-(node,head) online-softmax aggregation ----------------
struct AggState { float m, s, acc[8]; };

__device__ __forceinline__ void agg_edge(
    AggState& st, const float* va, const float* xd,
    const float* w0, const float* w1, const float* at,
    float ea0, float ea1)
{
    float lg = 0.f;
#pragma unroll
    for (int o = 0; o < 8; o++) {
        float mv = va[o] + xd[o] + (w0[o]*ea0 + w1[o]*ea1);
        mv = mv > 0.f ? mv : 0.2f*mv;      // leaky_relu 0.2
        lg += mv * at[o];
    }
    float nm = fmaxf(st.m, lg);
    float sc = __expf(st.m - nm);
    float wv = __expf(lg - nm);
    st.s = st.s*sc + wv;
#pragma unroll
    for (int o = 0; o < 8; o++) st.acc[o] = st.acc[o]*sc + wv*va[o];
    st.m = nm;
}

__device__ __forceinline__ void agg_one(
    AggState& st, uint2 r, uint2 g, const float* xd,
    const float* w0, const float* w1, const float* at)
{
    float v[8];
    unpack_fp8x8(g, v);
    __half2 h2 = *reinterpret_cast<__half2*>(&r.y);
    agg_edge(st, v, xd, w0, w1, at, __low2float(h2), __high2float(h2));
}

// online-softmax over one (node,head) row; hu is wave-uniform (SGPR)
__device__ __forceinline__ void agg_row(
    int rs, int re, int hu,
    const uint2* __restrict__ recs, const uint2* __restrict__ xl8,
    const float* xd, const float* w0, const float* w1, const float* at,
    AggState& st)
{
    st.m = -INFINITY; st.s = 0.f;
#pragma unroll
    for (int o = 0; o < 8; o++) st.acc[o] = 0.f;
    int i = rs;
    for (; i + 4 <= re; i += 4) {
        uint2 r0 = recs[i], r1 = recs[i+1], r2 = recs[i+2], r3 = recs[i+3];
        uint2 g0 = xl8[(size_t)r0.x*2 + hu];
        uint2 g1 = xl8[(size_t)r1.x*2 + hu];
        uint2 g2 = xl8[(size_t)r2.x*2 + hu];
        uint2 g3 = xl8[(size_t)r3.x*2 + hu];
        agg_one(st, r0, g0, xd, w0, w1, at);
        agg_one(st, r1, g1, xd, w0, w1, at);
        agg_one(st, r2, g2, xd, w0, w1, at);
        agg_one(st, r3, g3, xd, w0, w1, at);
    }
    for (; i < re; i++) {
        uint2 r0 = recs[i];
        uint2 g0 = xl8[(size_t)r0.x*2 + hu];
        agg_one(st, r0, g0, xd, w0, w1, at);
    }
}

// layer 1 fused: aggregate + lrelu(0.1) + layer-2 transform -> xlB(fp8), xr(in place)
// block = 128 nodes x 2 heads; waves 0-1: head 0, waves 2-3: head 1.
__global__ void __launch_bounds__(256, 4) node_agg_l1(
    const int* __restrict__ rowS, const int* __restrict__ rowE,
    const uint2* __restrict__ recs,
    const uint2* __restrict__ xlA, float* xr,
    const float* __restrict__ we, const float* __restrict__ att,
    const float* __restrict__ bias,
    const float* __restrict__ wl2, const float* __restrict__ bl2,
    const float* __restrict__ wr2, const float* __restrict__ br2,
    uint2* __restrict__ xlB, int N)
{
    __shared__ float sh[256][8];
    int t = threadIdx.x;
    int hu = __builtin_amdgcn_readfirstlane(t >> 7);   // wave-uniform head
    int n = blockIdx.x * 128 + (t & 127);
    bool alive = (n < N);
    int kb = hu * 8;
    float w0[8], w1[8], at[8];                          // SGPR (uniform idx)
#pragma unroll
    for (int o = 0; o < 8; o++) {
        w0[o] = we[2*(kb+o)];
        w1[o] = we[2*(kb+o)+1];
        at[o] = att[kb+o];
    }
    float xd[8];
    {
        size_t nn = alive ? (size_t)n : 0;
        const float4* xrp = (const float4*)(xr + nn*HO + kb);
        float4 d0 = xrp[0], d1 = xrp[1];
        xd[0]=d0.x; xd[1]=d0.y; xd[2]=d0.z; xd[3]=d0.w;
        xd[4]=d1.x; xd[5]=d1.y; xd[6]=d1.z; xd[7]=d1.w;
    }
    int rs = alive ? rowS[n] : 0;
    int re = alive ? rowE[n] : 0;
    AggState st;
    agg_row(rs, re, hu, recs, xlA, xd, w0, w1, at, st);

    float inv = 1.f/(st.s + 1e-16f);
    float hh[8];
#pragma unroll
    for (int o = 0; o < 8; o++) hh[o] = lrelu(st.acc[o]*inv + bias[kb+o], 0.1f);
    // exchange with the other head's thread (t ^ 128) via LDS
#pragma unroll
    for (int o = 0; o < 8; o++) sh[t][o] = hh[o];
    __syncthreads();
    if (!alive) return;
    int partner = t ^ 128;
    float h0v[8], h1v[8];
#pragma unroll
    for (int o = 0; o < 8; o++) {
        float oth = sh[partner][o];
        h0v[o] = hu ? oth : hh[o];
        h1v[o] = hu ? hh[o] : oth;
    }
    // layer-2 transform: this thread computes its head's 8 outputs of xl2, xr2
    float ol[8], orr[8];
#pragma unroll
    for (int jo = 0; jo < 8; jo++) {
        int j = kb + jo;
        float a = bl2[j], b = br2[j];
#pragma unroll
        for (int k = 0; k < 8; k++) { a += wl2[HO*j+k]*h0v[k];   b += wr2[HO*j+k]*h0v[k]; }
#pragma unroll
        for (int k = 0; k < 8; k++) { a += wl2[HO*j+8+k]*h1v[k]; b += wr2[HO*j+8+k]*h1v[k]; }
        ol[jo] = a; orr[jo] = b;
    }
    xlB[(size_t)n*2 + hu] = pack_fp8x8(ol);
    float4* xr4 = (float4*)(xr + (size_t)n*HO + kb);
    xr4[0] = make_float4(orr[0], orr[1], orr[2], orr[3]);
    xr4[1] = make_float4(orr[4], orr[5], orr[6], orr[7]);
}

// layer 2: aggregate (+bias), block-reduce, write partials column-major
__global__ void __launch_bounds__(256, 4) node_agg_l2(
    const int* __restrict__ rowS, const int* __restrict__ rowE,
    const uint2* __restrict__ recs,
    const uint2* __restrict__ xlB, const float* __restrict__ xr,
    const float* __restrict__ we, const float* __restrict__ att,
    const float* __restrict__ bias, float* __restrict__ partials, int pstride, int N)
{
    int t = threadIdx.x;
    int hu = __builtin_amdgcn_readfirstlane(t >> 7);   // wave-uniform head
    int n = blockIdx.x * 128 + (t & 127);
    bool alive = (n < N);
    int kb = hu * 8;
    float w0[8], w1[8], at[8];
#pragma unroll
    for (int o = 0; o < 8; o++) {
        w0[o] = we[2*(kb+o)];
        w1[o] = we[2*(kb+o)+1];
        at[o] = att[kb+o];
    }
    float xd[8];
    {
        size_t nn = alive ? (size_t)n : 0;
        const float4* xrp = (const float4*)(xr + nn*HO + kb);
        float4 d0 = xrp[0], d1 = xrp[1];
        xd[0]=d0.x; xd[1]=d0.y; xd[2]=d0.z; xd[3]=d0.w;
        xd[4]=d1.x; xd[5]=d1.y; xd[6]=d1.z; xd[7]=d1.w;
    }
    int rs = alive ? rowS[n] : 0;
    int re = alive ? rowE[n] : 0;
    AggState st;
    agg_row(rs, re, hu, recs, xlB, xd, w0, w1, at, st);

    float out[8];
    if (alive) {
        float inv = 1.f/(st.s + 1e-16f);
#pragma unroll
        for (int o = 0; o < 8; o++) out[o] = st.acc[o]*inv + bias[kb+o];
    } else {
#pragma unroll
        for (int o = 0; o < 8; o++) out[o] = 0.f;
    }
    // wave reduce (all lanes in a wave share the same head)
#pragma unroll
    for (int off = 32; off >= 1; off >>= 1) {
#pragma unroll
        for (int o = 0; o < 8; o++) out[o] += __shfl_down(out[o], off, 64);
    }
    __shared__ float sm[4][8];
    int wave = t >> 6, lane = t & 63;
    if (lane == 0) {
#pragma unroll
        for (int o = 0; o < 8; o++) sm[wave][o] = out[o];
    }
    __syncthreads();
    if (t < 16) {
        int hp = t >> 3, oo = t & 7;            // waves 0,1 = head0; 2,3 = head1
        float tt = sm[2*hp][oo] + sm[2*hp+1][oo];
        partials[(size_t)(hp*8 + oo) * pstride + blockIdx.x] = tt;
    }
}

// parallel partials fold: one block per column, coalesced reads
__global__ void __launch_bounds__(256) k_reduce(
    const float* __restrict__ partials, int pstride, int nparts,
    float* __restrict__ pool)
{
    __shared__ float s[256];
    int c = blockIdx.x;           // column 0..15
    int t = threadIdx.x;
    const float* col = partials + (size_t)c * pstride;
    float acc = 0.f;
    for (int r = t; r < nparts; r += 256) acc += col[r];
    s[t] = acc;
    __syncthreads();
#pragma unroll
    for (int off = 128; off > 0; off >>= 1) {
        if (t < off) s[t] += s[t + off];
        __syncthreads();
    }
    if (t == 0) pool[c] = s[0];
}

// ---------------- final tail (pool[16] precomputed) ----------------
__global__ void __launch_bounds__(64) final_mlp(
    const float* __restrict__ pool, const float* __restrict__ meta,
    const float* __restrict__ sp1_w, const float* __restrict__ sp1_b,
    const float* __restrict__ sp2_w, const float* __restrict__ sp2_b,
    const float* __restrict__ me_w, const float* __restrict__ me_b,
    const float* __restrict__ fc1_w, const float* __restrict__ fc1_b,
    const float* __restrict__ fc2_w, const float* __restrict__ fc2_b,
    const float* __restrict__ fc3_w, const float* __restrict__ fc3_b,
    float* __restrict__ out)
{
    __shared__ float s1[64], zb[24], z1[24], z2[8];
    int t = threadIdx.x;
    {
        float acc = sp1_b[t];
        for (int k = 0; k < 16; k++) acc += pool[k]*sp1_w[t*16+k];
        s1[t] = lrelu(acc, 0.1f);
    }
    __syncthreads();
    if (t < 16) {
        float acc = sp2_b[t];
        for (int k = 0; k < 64; k++) acc += s1[k]*sp2_w[t*64+k];
        zb[t] = acc;
    } else if (t < 24) {
        int j = t - 16;
        float acc = me_b[j];
        for (int k = 0; k < 6; k++) acc += meta[k]*me_w[j*6+k];
        zb[t] = lrelu(acc, 0.1f);
    }
    __syncthreads();
    if (t < 24) {
        float acc = fc1_b[t];
        for (int k = 0; k < 24; k++) acc += zb[k]*fc1_w[t*24+k];
        z1[t] = lrelu(acc, 0.1f);
    }
    __syncthreads();
    if (t < 8) {
        float acc = fc2_b[t];
        for (int k = 0; k < 24; k++) acc += z1[k]*fc2_w[t*24+k];
        z2[t] = lrelu(acc, 0.1f);
    }
    __syncthreads();
    if (t == 0) {
        float z3[3]; float mxv = -1e30f;
        for (int j = 0; j < 3; j++) {
            float acc = fc3_b[j];
            for (int k = 0; k < 8; k++) acc += z2[k]*fc3_w[j*8+k];
            z3[j] = acc; mxv = fmaxf(mxv, acc);
        }
        float s = 0.f;
        for (int j = 0; j < 3; j++) { z3[j] = __expf(z3[j]-mxv); s += z3[j]; }
        for (int j = 0; j < 3; j++) out[j] = z3[j]/s;
    }
}

extern "C" void kernel_launch(void* const* d_in, const int* in_sizes, int n_in,
                              void* d_out, int out_size, void* d_ws, size_t ws_size,
                              hipStream_t stream)
{
    const float* x      = (const float*)d_in[0];
    const int*   eidx   = (const int*)  d_in[1];
    const float* eattr  = (const float*)d_in[2];
    const float* meta   = (const float*)d_in[3];
    const float* ft1_w  = (const float*)d_in[4];
    const float* ft1_b  = (const float*)d_in[5];
    const float* ft2_w  = (const float*)d_in[6];
    const float* ft2_b  = (const float*)d_in[7];
    const float* g1_wl  = (const float*)d_in[8];
    const float* g1_bl  = (const float*)d_in[9];
    const float* g1_wr  = (const float*)d_in[10];
    const float* g1_br  = (const float*)d_in[11];
    const float* g1_we  = (const float*)d_in[12];
    const float* g1_att = (const float*)d_in[13];
    const float* g1_bias= (const float*)d_in[14];
    const float* g2_wl  = (const float*)d_in[15];
    const float* g2_bl  = (const float*)d_in[16];
    const float* g2_wr  = (const float*)d_in[17];
    const float* g2_br  = (const float*)d_in[18];
    const float* g2_we  = (const float*)d_in[19];
    const float* g2_att = (const float*)d_in[20];
    const float* g2_bias= (const float*)d_in[21];
    const float* sp1_w  = (const float*)d_in[22];
    const float* sp1_b  = (const float*)d_in[23];
    const float* sp2_w  = (const float*)d_in[24];
    const float* sp2_b  = (const float*)d_in[25];
    const float* me_w   = (const float*)d_in[26];
    const float* me_b   = (const float*)d_in[27];
    const float* fc1_w  = (const float*)d_in[28];
    const float* fc1_b  = (const float*)d_in[29];
    const float* fc2_w  = (const float*)d_in[30];
    const float* fc2_b  = (const float*)d_in[31];
    const float* fc3_w  = (const float*)d_in[32];
    const float* fc3_b  = (const float*)d_in[33];
    float* out = (float*)d_out;

    const int N = in_sizes[0] / 3;
    const int E = in_sizes[2] / 2;
    const int* src = eidx;
    const int* dst = eidx + E;

    const int BN    = (N + 255) / 256;
    const int BN2   = (2*N + 255) / 256;           // agg kernels: 2 threads/node
    const int NBUCK = (N + BNODES - 1) >> BSHIFT;  // 977 (<= 1024)
    const int BP    = (E + PCHUNK - 1) / PCHUNK;   // partition blocks
    const int pstride = (BN2 + 63) & ~63;          // column-major partials stride

    // workspace layout (256B-aligned):
    char* w = (char*)d_ws;
    size_t off = 0;
    auto take = [&](size_t bytes) { size_t o = off; off += (bytes + 255) & ~(size_t)255; return o; };
    int*    rowS     = (int*)   (w + take((size_t)4*N));
    int*    rowE     = (int*)   (w + take((size_t)4*N));
    int*    bcur     = (int*)   (w + take(4096));
    float*  pool     = (float*) (w + take(64));
    float*  partials = (float*) (w + take((size_t)4*16*pstride));
    uint2*  recs     = (uint2*) (w + take((size_t)8*NBUCK*CAP2));  // padded regions
    uint2*  xlA      = (uint2*) (w + take((size_t)16*N));          // fp8 table, layer 1
    uint2*  xlB      = (uint2*) (w + take((size_t)16*N));          // fp8 table, layer 2
    float*  xr       = (float*) (w + take((size_t)64*N));          // fp32, in-place update
    // total ~= 2MB + 45MB + 4MB + 4MB + 16MB ~= 71MB

    // node features + layer-1 transforms
    node_l1<<<BN, 256, 0, stream>>>(x, ft1_w, ft1_b, ft2_w, ft2_b,
                                    g1_wl, g1_bl, g1_wr, g1_br, xlA, xr, N);
    // two-phase dst-sort into padded bucket regions (graph-only; shared by both layers)
    k_binit<<<4, 256, 0, stream>>>(bcur);
    k_part<<<BP, PT, 0, stream>>>(src, dst, eattr, bcur, recs, E);
    k_fine<<<NBUCK, 256, 0, stream>>>(bcur, recs, rowS, rowE, N);

    // ---- layer 1 (agg + act + layer-2 transform fused) ----
    node_agg_l1<<<BN2, 256, 0, stream>>>(rowS, rowE, recs, xlA, xr,
                                         g1_we, g1_att, g1_bias,
                                         g2_wl, g2_bl, g2_wr, g2_br, xlB, N);
    // ---- layer 2 ----
    node_agg_l2<<<BN2, 256, 0, stream>>>(rowS, rowE, recs, xlB, xr,
                                         g2_we, g2_att, g2_bias, partials, pstride, N);
    // ---- tail ----
    k_reduce<<<16, 256, 0, stream>>>(partials, pstride, BN2, pool);
    final_mlp<<<1, 64, 0, stream>>>(pool, meta, sp1_w, sp1_b, sp2_w, sp2_b,
                                    me_w, me_b, fc1_w, fc1_b, fc2_w, fc2_b,
                                    fc3_w, fc3_b, out);
}

// Round 9
// 438.625 us; speedup vs baseline: 1.0621x; 1.0224x over previous
//
#include <hip/hip_runtime.h>
#include <hip/hip_bf16.h>
#include <hip/hip_fp16.h>
#include <math.h>

// SportsGNN: ftMLP -> GATv2 x2 -> sumpool -> MLP -> softmax
// N=250000, E=5000000, H=2, O=8 (HO=16)
// Round-18: r17 skeleton (wave-uniform head, (256,4), no spill: VGPR~52
// confirmed) with two orthogonal cost cuts:
//  1. PACKED FP32 agg inner loop: keep fp8-unpack results as v2f pairs,
//     compute logit + online-softmax accumulate with v_pk_fma/pk_mul/pk_max
//     (lrelu(x) = max(x, 0.2x)). Halves hot-loop VALU instrs (~50 -> ~26).
//  2. Wave-shfl prefix scans in k_part / k_fine: 18/16 block barriers -> 2.
//     (Sort kernels are the unprofiled ~100+ us of the pipeline.)

#define HO 16
#define BSHIFT 8
#define BNODES 256
#define PT 512          // k_part threads
#define PCHUNK 6144     // edges per partition block
#define CAP2 6016       // per-bucket record capacity (mean ~5117, +12.6 sigma)

typedef __attribute__((ext_vector_type(2))) float v2f;

__device__ __forceinline__ float lrelu(float x, float s) { return x > 0.f ? x : s * x; }

// pack 8 floats -> 8 fp8 bytes (e4m3 HW rounding)
__device__ __forceinline__ uint2 pack_fp8x8(const float* v) {
    int a = __builtin_amdgcn_cvt_pk_fp8_f32(v[0], v[1], 0, false);
    a     = __builtin_amdgcn_cvt_pk_fp8_f32(v[2], v[3], a, true);
    int b = __builtin_amdgcn_cvt_pk_fp8_f32(v[4], v[5], 0, false);
    b     = __builtin_amdgcn_cvt_pk_fp8_f32(v[6], v[7], b, true);
    return make_uint2((unsigned int)a, (unsigned int)b);
}

// unpack 8 fp8 bytes -> 4 x v2f (stay packed for VOP3P math)
__device__ __forceinline__ void unpack_fp8x8v(uint2 u, v2f* v) {
    v[0] = __builtin_amdgcn_cvt_pk_f32_fp8((int)u.x, false);
    v[1] = __builtin_amdgcn_cvt_pk_f32_fp8((int)u.x, true);
    v[2] = __builtin_amdgcn_cvt_pk_f32_fp8((int)u.y, false);
    v[3] = __builtin_amdgcn_cvt_pk_f32_fp8((int)u.y, true);
}

// ---------------- node kernel, layer 1: x[N,3] -> ftMLP -> xlA(fp8), xr(fp32) ----------------
__global__ void __launch_bounds__(256) node_l1(
    const float* __restrict__ x,
    const float* __restrict__ ft1_w, const float* __restrict__ ft1_b,
    const float* __restrict__ ft2_w, const float* __restrict__ ft2_b,
    const float* __restrict__ wl, const float* __restrict__ bl,
    const float* __restrict__ wr, const float* __restrict__ br,
    uint2* __restrict__ xlA, float* __restrict__ xr, int N)
{
    int n = blockIdx.x * 256 + threadIdx.x;
    if (n >= N) return;
    float x0 = x[3*n], x1 = x[3*n+1], x2 = x[3*n+2];
    float h1[8];
#pragma unroll
    for (int j = 0; j < 8; j++) {
        float a = ft1_w[3*j]*x0 + ft1_w[3*j+1]*x1 + ft1_w[3*j+2]*x2 + ft1_b[j];
        h1[j] = lrelu(a, 0.1f);
    }
    float h2[8];
#pragma unroll
    for (int j = 0; j < 8; j++) {
        float a = ft2_b[j];
#pragma unroll
        for (int k = 0; k < 8; k++) a += ft2_w[8*j+k]*h1[k];
        h2[j] = lrelu(a, 0.1f);
    }
    float ol[HO], orr[HO];
#pragma unroll
    for (int j = 0; j < HO; j++) {
        float a = bl[j], b = br[j];
#pragma unroll
        for (int k = 0; k < 8; k++) { a += wl[8*j+k]*h2[k]; b += wr[8*j+k]*h2[k]; }
        ol[j] = a; orr[j] = b;
    }
    uint2 p0 = pack_fp8x8(ol);
    uint2 p1 = pack_fp8x8(ol + 8);
    ((uint4*)xlA)[n] = make_uint4(p0.x, p0.y, p1.x, p1.y);
    float4* xr4 = (float4*)(xr + (size_t)n*HO);
#pragma unroll
    for (int q = 0; q < 4; q++)
        xr4[q] = make_float4(orr[4*q], orr[4*q+1], orr[4*q+2], orr[4*q+3]);
}

// bucket cursors: bcur[b] = b*CAP2 (start of each padded region)
__global__ void __launch_bounds__(256) k_binit(int* __restrict__ bcur)
{
    int b = blockIdx.x * 256 + threadIdx.x;
    if (b < 1024) bcur[b] = b * CAP2;
}

// ---------------- phase 1: LDS multisplit into padded bucket regions ----------------
// out rec: .x = (src<<8)|(dst&255), .y = half2(eattr)
__global__ void __launch_bounds__(PT) k_part(
    const int* __restrict__ src, const int* __restrict__ dst,
    const float* __restrict__ eattr, int* __restrict__ bcur,
    uint2* __restrict__ grecs, int E)
{
    __shared__ int hist[1024], lofs[1024], gofs[1024], lcur[1024];
    __shared__ int wsum[8];
    __shared__ uint2 srecs[PCHUNK];
    __shared__ unsigned short bid[PCHUNK];
    int t = threadIdx.x;
    int base = blockIdx.x * PCHUNK;
    int cnt = E - base; if (cnt > PCHUNK) cnt = PCHUNK;

    for (int b = t; b < 1024; b += PT) hist[b] = 0;
    __syncthreads();
    for (int i = t; i < cnt; i += PT)
        atomicAdd(&hist[dst[base + i] >> BSHIFT], 1);
    __syncthreads();
    int h0 = hist[2*t], h1 = hist[2*t+1];
    int pair = h0 + h1;
    // wave-level inclusive shfl scan (no barriers), then cross-wave combine
    int lane = t & 63;
    int v = pair;
#pragma unroll
    for (int off = 1; off < 64; off <<= 1) {
        int u = __shfl_up(v, off, 64);
        if (lane >= off) v += u;
    }
    if (lane == 63) wsum[t >> 6] = v;
    __syncthreads();
    if (t == 0) {
        int run = 0;
#pragma unroll
        for (int w8 = 0; w8 < 8; w8++) { int xv = wsum[w8]; wsum[w8] = run; run += xv; }
    }
    __syncthreads();
    int pbase = v + wsum[t >> 6] - pair;   // exclusive prefix of pairs
    lofs[2*t]   = pbase;
    lofs[2*t+1] = pbase + h0;
    __syncthreads();
    for (int b = t; b < 1024; b += PT) {
        int c = hist[b];
        int g = (c > 0) ? atomicAdd(&bcur[b], c) : 0;
        gofs[b] = g - lofs[b];
        lcur[b] = 0;
    }
    __syncthreads();
    for (int i = t; i < cnt; i += PT) {
        int e = base + i;
        int d = dst[e];
        int b = d >> BSHIFT;
        float2 ea = ((const float2*)eattr)[e];
        __half2 hv = __floats2half2_rn(ea.x, ea.y);
        unsigned int eb = *reinterpret_cast<unsigned int*>(&hv);
        int q = atomicAdd(&lcur[b], 1);
        int idx = lofs[b] + q;
        srecs[idx] = make_uint2(((unsigned int)src[e] << 8) | (unsigned int)(d & (BNODES-1)), eb);
        bid[idx] = (unsigned short)b;
    }
    __syncthreads();
    for (int i = t; i < cnt; i += PT) {
        int b = bid[i];
        int pos = gofs[b] + i;
        if (pos < (b + 1) * CAP2) grecs[pos] = srecs[i];
    }
}

// ---------------- phase 2: per-bucket in-LDS node sort + rowS/rowE emission ----------------
__global__ void __launch_bounds__(256) k_fine(
    const int* __restrict__ bcur, uint2* recs,
    int* __restrict__ rowS, int* __restrict__ rowE, int N)
{
    __shared__ uint2 rout[CAP2];
    __shared__ int lhist[256], lcur2[256];
    __shared__ int wsum[4];
    int b = blockIdx.x;
    int bstart = b * CAP2;
    int cnt = bcur[b] - bstart;
    if (cnt > CAP2) cnt = CAP2;
    if (cnt < 0) cnt = 0;
    int t = threadIdx.x;
    lhist[t] = 0;
    __syncthreads();
    for (int i = t; i < cnt; i += 256)
        atomicAdd(&lhist[recs[bstart + i].x & (BNODES-1)], 1);
    __syncthreads();
    int v = lhist[t];
    // wave shfl scan + cross-wave combine (2 barriers total)
    int lane = t & 63;
    int sv = v;
#pragma unroll
    for (int off = 1; off < 64; off <<= 1) {
        int u = __shfl_up(sv, off, 64);
        if (lane >= off) sv += u;
    }
    if (lane == 63) wsum[t >> 6] = sv;
    __syncthreads();
    if (t == 0) {
        int run = 0;
#pragma unroll
        for (int w4 = 0; w4 < 4; w4++) { int xv = wsum[w4]; wsum[w4] = run; run += xv; }
    }
    __syncthreads();
    int ex = sv + wsum[t >> 6] - v;        // exclusive in-bucket prefix
    lcur2[t] = ex;
    int n = (b << BSHIFT) + t;
    if (n < N) { rowS[n] = bstart + ex; rowE[n] = bstart + ex + v; }
    __syncthreads();
    for (int i = t; i < cnt; i += 256) {
        uint2 r = recs[bstart + i];
        int p = atomicAdd(&lcur2[r.x & (BNODES-1)], 1);
        rout[p] = make_uint2(r.x >> 8, r.y);
    }
    __syncthreads();
    for (int i = t; i < cnt; i += 256)
        recs[bstart + i] = rout[i];
}

// ---------------- per-(node,head) online-softmax aggregation (packed f32) ----------------
struct AggState { float m, s; v2f acc[4]; };

__device__ __forceinline__ void agg_edge(
    AggState& st, const v2f* va, const v2f* xd,
    const v2f* w0, const v2f* w1, const v2f* at,
    float ea0, float ea1)
{
    v2f lg2 = {0.f, 0.f};
#pragma unroll
    for (int q = 0; q < 4; q++) {
        v2f mv = va[q] + xd[q] + w0[q]*ea0 + w1[q]*ea1;   // pk_add + 2x pk_fma
        mv = __builtin_elementwise_max(mv, mv * 0.2f);    // lrelu = max(x, 0.2x)
        lg2 = lg2 + mv*at[q];                              // pk_fma
    }
    float lg = lg2.x + lg2.y;
    float nm = fmaxf(st.m, lg);
    float sc = __expf(st.m - nm);
    float wv = __expf(lg - nm);
    st.s = st.s*sc + wv;
#pragma unroll
    for (int q = 0; q < 4; q++) st.acc[q] = st.acc[q]*sc + va[q]*wv;  // pk_mul + pk_fma
    st.m = nm;
}

__device__ __forceinline__ void agg_one(
    AggState& st, uint2 r, uint2 g, const v2f* xd,
    const v2f* w0, const v2f* w1, const v2f* at)
{
    v2f v[4];
    unpack_fp8x8v(g, v);
    __half2 h2 = *reinterpret_cast<__half2*>(&r.y);
    agg_edge(st, v, xd, w0, w1, at, __low2float(h2), __high2float(h2));
}

// online-softmax over one (node,head) row; hu is wave-uniform (SGPR)
__device__ __forceinline__ void agg_row(
    int rs, int re, int hu,
    const uint2* __restrict__ recs, const uint2* __restrict__ xl8,
    const v2f* xd, const v2f* w0, const v2f* w1, const v2f* at,
    AggState& st)
{
    st.m = -INFINITY; st.s = 0.f;
#pragma unroll
    for (int q = 0; q < 4; q++) st.acc[q] = (v2f){0.f, 0.f};
    int i = rs;
    for (; i + 4 <= re; i += 4) {
        uint2 r0 = recs[i], r1 = recs[i+1], r2 = recs[i+2], r3 = recs[i+3];
        uint2 g0 = xl8[(size_t)r0.x*2 + hu];
        uint2 g1 = xl8[(size_t)r1.x*2 + hu];
        uint2 g2 = xl8[(size_t)r2.x*2 + hu];
        uint2 g3 = xl8[(size_t)r3.x*2 + hu];
        agg_one(st, r0, g0, xd, w0, w1, at);
        agg_one(st, r1, g1, xd, w0, w1, at);
        agg_one(st, r2, g2, xd, w0, w1, at);
        agg_one(st, r3, g3, xd, w0, w1, at);
    }
    for (; i < re; i++) {
        uint2 r0 = recs[i];
        uint2 g0 = xl8[(size_t)r0.x*2 + hu];
        agg_one(st, r0, g0, xd, w0, w1, at);
    }
}

// layer 1 fused: aggregate + lrelu(0.1) + layer-2 transform -> xlB(fp8), xr(in place)
// block = 128 nodes x 2 heads; waves 0-1: head 0, waves 2-3: head 1.
__global__ void __launch_bounds__(256, 4) node_agg_l1(
    const int* __restrict__ rowS, const int* __restrict__ rowE,
    const uint2* __restrict__ recs,
    const uint2* __restrict__ xlA, float* xr,
    const float* __restrict__ we, const float* __restrict__ att,
    const float* __restrict__ bias,
    const float* __restrict__ wl2, const float* __restrict__ bl2,
    const float* __restrict__ wr2, const float* __restrict__ br2,
    uint2* __restrict__ xlB, int N)
{
    __shared__ float sh[256][8];
    int t = threadIdx.x;
    int hu = __builtin_amdgcn_readfirstlane(t >> 7);   // wave-uniform head
    int n = blockIdx.x * 128 + (t & 127);
    bool alive = (n < N);
    int kb = hu * 8;
    v2f w0[4], w1[4], at[4];                            // uniform idx -> SGPR
#pragma unroll
    for (int q = 0; q < 4; q++) {
        int o = kb + 2*q;
        w0[q] = (v2f){we[2*o],   we[2*(o+1)]};
        w1[q] = (v2f){we[2*o+1], we[2*(o+1)+1]};
        at[q] = (v2f){att[o],    att[o+1]};
    }
    v2f xd[4];
    {
        size_t nn = alive ? (size_t)n : 0;
        const float4* xrp = (const float4*)(xr + nn*HO + kb);
        float4 d0 = xrp[0], d1 = xrp[1];
        xd[0] = (v2f){d0.x, d0.y}; xd[1] = (v2f){d0.z, d0.w};
        xd[2] = (v2f){d1.x, d1.y}; xd[3] = (v2f){d1.z, d1.w};
    }
    int rs = alive ? rowS[n] : 0;
    int re = alive ? rowE[n] : 0;
    AggState st;
    agg_row(rs, re, hu, recs, xlA, xd, w0, w1, at, st);

    float inv = 1.f/(st.s + 1e-16f);
    float accs[8] = {st.acc[0].x, st.acc[0].y, st.acc[1].x, st.acc[1].y,
                     st.acc[2].x, st.acc[2].y, st.acc[3].x, st.acc[3].y};
    float hh[8];
#pragma unroll
    for (int o = 0; o < 8; o++) hh[o] = lrelu(accs[o]*inv + bias[kb+o], 0.1f);
    // exchange with the other head's thread (t ^ 128) via LDS
#pragma unroll
    for (int o = 0; o < 8; o++) sh[t][o] = hh[o];
    __syncthreads();
    if (!alive) return;
    int partner = t ^ 128;
    float h0v[8], h1v[8];
#pragma unroll
    for (int o = 0; o < 8; o++) {
        float oth = sh[partner][o];
        h0v[o] = hu ? oth : hh[o];
        h1v[o] = hu ? hh[o] : oth;
    }
    // layer-2 transform: this thread computes its head's 8 outputs of xl2, xr2
    float ol[8], orr[8];
#pragma unroll
    for (int jo = 0; jo < 8; jo++) {
        int j = kb + jo;
        float a = bl2[j], b = br2[j];
#pragma unroll
        for (int k = 0; k < 8; k++) { a += wl2[HO*j+k]*h0v[k];   b += wr2[HO*j+k]*h0v[k]; }
#pragma unroll
        for (int k = 0; k < 8; k++) { a += wl2[HO*j+8+k]*h1v[k]; b += wr2[HO*j+8+k]*h1v[k]; }
        ol[jo] = a; orr[jo] = b;
    }
    xlB[(size_t)n*2 + hu] = pack_fp8x8(ol);
    float4* xr4 = (float4*)(xr + (size_t)n*HO + kb);
    xr4[0] = make_float4(orr[0], orr[1], orr[2], orr[3]);
    xr4[1] = make_float4(orr[4], orr[5], orr[6], orr[7]);
}

// layer 2: aggregate (+bias), block-reduce, write partials column-major
__global__ void __launch_bounds__(256, 4) node_agg_l2(
    const int* __restrict__ rowS, const int* __restrict__ rowE,
    const uint2* __restrict__ recs,
    const uint2* __restrict__ xlB, const float* __restrict__ xr,
    const float* __restrict__ we, const float* __restrict__ att,
    const float* __restrict__ bias, float* __restrict__ partials, int pstride, int N)
{
    int t = threadIdx.x;
    int hu = __builtin_amdgcn_readfirstlane(t >> 7);   // wave-uniform head
    int n = blockIdx.x * 128 + (t & 127);
    bool alive = (n < N);
    int kb = hu * 8;
    v2f w0[4], w1[4], at[4];
#pragma unroll
    for (int q = 0; q < 4; q++) {
        int o = kb + 2*q;
        w0[q] = (v2f){we[2*o],   we[2*(o+1)]};
        w1[q] = (v2f){we[2*o+1], we[2*(o+1)+1]};
        at[q] = (v2f){att[o],    att[o+1]};
    }
    v2f xd[4];
    {
        size_t nn = alive ? (size_t)n : 0;
        const float4* xrp = (const float4*)(xr + nn*HO + kb);
        float4 d0 = xrp[0], d1 = xrp[1];
        xd[0] = (v2f){d0.x, d0.y}; xd[1] = (v2f){d0.z, d0.w};
        xd[2] = (v2f){d1.x, d1.y}; xd[3] = (v2f){d1.z, d1.w};
    }
    int rs = alive ? rowS[n] : 0;
    int re = alive ? rowE[n] : 0;
    AggState st;
    agg_row(rs, re, hu, recs, xlB, xd, w0, w1, at, st);

    float out[8];
    if (alive) {
        float inv = 1.f/(st.s + 1e-16f);
        float accs[8] = {st.acc[0].x, st.acc[0].y, st.acc[1].x, st.acc[1].y,
                         st.acc[2].x, st.acc[2].y, st.acc[3].x, st.acc[3].y};
#pragma unroll
        for (int o = 0; o < 8; o++) out[o] = accs[o]*inv + bias[kb+o];
    } else {
#pragma unroll
        for (int o = 0; o < 8; o++) out[o] = 0.f;
    }
    // wave reduce (all lanes in a wave share the same head)
#pragma unroll
    for (int off = 32; off >= 1; off >>= 1) {
#pragma unroll
        for (int o = 0; o < 8; o++) out[o] += __shfl_down(out[o], off, 64);
    }
    __shared__ float sm[4][8];
    int wave = t >> 6, lane = t & 63;
    if (lane == 0) {
#pragma unroll
        for (int o = 0; o < 8; o++) sm[wave][o] = out[o];
    }
    __syncthreads();
    if (t < 16) {
        int hp = t >> 3, oo = t & 7;            // waves 0,1 = head0; 2,3 = head1
        float tt = sm[2*hp][oo] + sm[2*hp+1][oo];
        partials[(size_t)(hp*8 + oo) * pstride + blockIdx.x] = tt;
    }
}

// parallel partials fold: one block per column, coalesced reads
__global__ void __launch_bounds__(256) k_reduce(
    const float* __restrict__ partials, int pstride, int nparts,
    float* __restrict__ pool)
{
    __shared__ float s[256];
    int c = blockIdx.x;           // column 0..15
    int t = threadIdx.x;
    const float* col = partials + (size_t)c * pstride;
    float acc = 0.f;
    for (int r = t; r < nparts; r += 256) acc += col[r];
    s[t] = acc;
    __syncthreads();
#pragma unroll
    for (int off = 128; off > 0; off >>= 1) {
        if (t < off) s[t] += s[t + off];
        __syncthreads();
    }
    if (t == 0) pool[c] = s[0];
}

// ---------------- final tail (pool[16] precomputed) ----------------
__global__ void __launch_bounds__(64) final_mlp(
    const float* __restrict__ pool, const float* __restrict__ meta,
    const float* __restrict__ sp1_w, const float* __restrict__ sp1_b,
    const float* __restrict__ sp2_w, const float* __restrict__ sp2_b,
    const float* __restrict__ me_w, const float* __restrict__ me_b,
    const float* __restrict__ fc1_w, const float* __restrict__ fc1_b,
    const float* __restrict__ fc2_w, const float* __restrict__ fc2_b,
    const float* __restrict__ fc3_w, const float* __restrict__ fc3_b,
    float* __restrict__ out)
{
    __shared__ float s1[64], zb[24], z1[24], z2[8];
    int t = threadIdx.x;
    {
        float acc = sp1_b[t];
        for (int k = 0; k < 16; k++) acc += pool[k]*sp1_w[t*16+k];
        s1[t] = lrelu(acc, 0.1f);
    }
    __syncthreads();
    if (t < 16) {
        float acc = sp2_b[t];
        for (int k = 0; k < 64; k++) acc += s1[k]*sp2_w[t*64+k];
        zb[t] = acc;
    } else if (t < 24) {
        int j = t - 16;
        float acc = me_b[j];
        for (int k = 0; k < 6; k++) acc += meta[k]*me_w[j*6+k];
        zb[t] = lrelu(acc, 0.1f);
    }
    __syncthreads();
    if (t < 24) {
        float acc = fc1_b[t];
        for (int k = 0; k < 24; k++) acc += zb[k]*fc1_w[t*24+k];
        z1[t] = lrelu(acc, 0.1f);
    }
    __syncthreads();
    if (t < 8) {
        float acc = fc2_b[t];
        for (int k = 0; k < 24; k++) acc += z1[k]*fc2_w[t*24+k];
        z2[t] = lrelu(acc, 0.1f);
    }
    __syncthreads();
    if (t == 0) {
        float z3[3]; float mxv = -1e30f;
        for (int j = 0; j < 3; j++) {
            float acc = fc3_b[j];
            for (int k = 0; k < 8; k++) acc += z2[k]*fc3_w[j*8+k];
            z3[j] = acc; mxv = fmaxf(mxv, acc);
        }
        float s = 0.f;
        for (int j = 0; j < 3; j++) { z3[j] = __expf(z3[j]-mxv); s += z3[j]; }
        for (int j = 0; j < 3; j++) out[j] = z3[j]/s;
    }
}

extern "C" void kernel_launch(void* const* d_in, const int* in_sizes, int n_in,
                              void* d_out, int out_size, void* d_ws, size_t ws_size,
                              hipStream_t stream)
{
    const float* x      = (const float*)d_in[0];
    const int*   eidx   = (const int*)  d_in[1];
    const float* eattr  = (const float*)d_in[2];
    const float* meta   = (const float*)d_in[3];
    const float* ft1_w  = (const float*)d_in[4];
    const float* ft1_b  = (const float*)d_in[5];
    const float* ft2_w  = (const float*)d_in[6];
    const float* ft2_b  = (const float*)d_in[7];
    const float* g1_wl  = (const float*)d_in[8];
    const float* g1_bl  = (const float*)d_in[9];
    const float* g1_wr  = (const float*)d_in[10];
    const float* g1_br  = (const float*)d_in[11];
    const float* g1_we  = (const float*)d_in[12];
    const float* g1_att = (const float*)d_in[13];
    const float* g1_bias= (const float*)d_in[14];
    const float* g2_wl  = (const float*)d_in[15];
    const float* g2_bl  = (const float*)d_in[16];
    const float* g2_wr  = (const float*)d_in[17];
    const float* g2_br  = (const float*)d_in[18];
    const float* g2_we  = (const float*)d_in[19];
    const float* g2_att = (const float*)d_in[20];
    const float* g2_bias= (const float*)d_in[21];
    const float* sp1_w  = (const float*)d_in[22];
    const float* sp1_b  = (const float*)d_in[23];
    const float* sp2_w  = (const float*)d_in[24];
    const float* sp2_b  = (const float*)d_in[25];
    const float* me_w   = (const float*)d_in[26];
    const float* me_b   = (const float*)d_in[27];
    const float* fc1_w  = (const float*)d_in[28];
    const float* fc1_b  = (const float*)d_in[29];
    const float* fc2_w  = (const float*)d_in[30];
    const float* fc2_b  = (const float*)d_in[31];
    const float* fc3_w  = (const float*)d_in[32];
    const float* fc3_b  = (const float*)d_in[33];
    float* out = (float*)d_out;

    const int N = in_sizes[0] / 3;
    const int E = in_sizes[2] / 2;
    const int* src = eidx;
    const int* dst = eidx + E;

    const int BN    = (N + 255) / 256;
    const int BN2   = (2*N + 255) / 256;           // agg kernels: 2 threads/node
    const int NBUCK = (N + BNODES - 1) >> BSHIFT;  // 977 (<= 1024)
    const int BP    = (E + PCHUNK - 1) / PCHUNK;   // partition blocks
    const int pstride = (BN2 + 63) & ~63;          // column-major partials stride

    // workspace layout (256B-aligned):
    char* w = (char*)d_ws;
    size_t off = 0;
    auto take = [&](size_t bytes) { size_t o = off; off += (bytes + 255) & ~(size_t)255; return o; };
    int*    rowS     = (int*)   (w + take((size_t)4*N));
    int*    rowE     = (int*)   (w + take((size_t)4*N));
    int*    bcur     = (int*)   (w + take(4096));
    float*  pool     = (float*) (w + take(64));
    float*  partials = (float*) (w + take((size_t)4*16*pstride));
    uint2*  recs     = (uint2*) (w + take((size_t)8*NBUCK*CAP2));  // padded regions
    uint2*  xlA      = (uint2*) (w + take((size_t)16*N));          // fp8 table, layer 1
    uint2*  xlB      = (uint2*) (w + take((size_t)16*N));          // fp8 table, layer 2
    float*  xr       = (float*) (w + take((size_t)64*N));          // fp32, in-place update
    // total ~= 2MB + 45MB + 4MB + 4MB + 16MB ~= 71MB

    // node features + layer-1 transforms
    node_l1<<<BN, 256, 0, stream>>>(x, ft1_w, ft1_b, ft2_w, ft2_b,
                                    g1_wl, g1_bl, g1_wr, g1_br, xlA, xr, N);
    // two-phase dst-sort into padded bucket regions (graph-only; shared by both layers)
    k_binit<<<4, 256, 0, stream>>>(bcur);
    k_part<<<BP, PT, 0, stream>>>(src, dst, eattr, bcur, recs, E);
    k_fine<<<NBUCK, 256, 0, stream>>>(bcur, recs, rowS, rowE, N);

    // ---- layer 1 (agg + act + layer-2 transform fused) ----
    node_agg_l1<<<BN2, 256, 0, stream>>>(rowS, rowE, recs, xlA, xr,
                                         g1_we, g1_att, g1_bias,
                                         g2_wl, g2_bl, g2_wr, g2_br, xlB, N);
    // ---- layer 2 ----
    node_agg_l2<<<BN2, 256, 0, stream>>>(rowS, rowE, recs, xlB, xr,
                                         g2_we, g2_att, g2_bias, partials, pstride, N);
    // ---- tail ----
    k_reduce<<<16, 256, 0, stream>>>(partials, pstride, BN2, pool);
    final_mlp<<<1, 64, 0, stream>>>(pool, meta, sp1_w, sp1_b, sp2_w, sp2_b,
                                    me_w, me_b, fc1_w, fc1_b, fc2_w, fc2_b,
                                    fc3_w, fc3_b, out);
}